// Round 2
// baseline (308.577 us; speedup 1.0000x reference)
//
#include <hip/hip_runtime.h>

#define N_NODES 100000
#define N_EDGES 1000000
#define D 64

// Kernel 1: out = (1+eps) * x, float4-vectorized.
__global__ __launch_bounds__(256) void gine_init(const float* __restrict__ x,
                                                 const float* __restrict__ eps,
                                                 float* __restrict__ out, int n4) {
    int i = blockIdx.x * blockDim.x + threadIdx.x;
    float s = 1.0f + eps[0];
    if (i < n4) {
        float4 v = ((const float4*)x)[i];
        v.x *= s; v.y *= s; v.z *= s; v.w *= s;
        ((float4*)out)[i] = v;
    }
}

// Kernel 2: per-edge scatter. One wave per edge, lane = feature dim.
// Coalesced gather of x[src] and edge_attr[e], coalesced atomicAdd to out[dst].
// NOTE: harness delivers integer inputs as int32 (reference int64 is narrowed).
__global__ __launch_bounds__(256) void gine_edges(const float* __restrict__ x,
                                                  const int* __restrict__ ei,
                                                  const float* __restrict__ ea,
                                                  float* __restrict__ out) {
    int e = blockIdx.x * (blockDim.x >> 6) + (threadIdx.x >> 6);
    int d = threadIdx.x & 63;
    if (e < N_EDGES) {
        int s = ei[e];              // src (row 0)
        int t = ei[N_EDGES + e];    // dst (row 1)
        float m = x[(long long)s * D + d] + ea[(long long)e * D + d];
        m = fmaxf(m, 0.0f);
        atomicAdd(&out[(long long)t * D + d], m);
    }
}

// Kernel 3: in-place out = relu(out @ W.T + b). One wave per row.
// Within a wave all loads of the row complete before the store (lockstep +
// data dependency), so in-place is safe; each row owned by exactly one wave.
__global__ __launch_bounds__(256) void gine_linear(float* __restrict__ h,
                                                   const float* __restrict__ W,
                                                   const float* __restrict__ b) {
    __shared__ float Wl[D][D + 1];  // +1 pad: bank = (o+d)%32, conflict-free
    __shared__ float bl[D];
    int tid = threadIdx.x;
    for (int i = tid; i < D * D; i += 256) {
        Wl[i >> 6][i & 63] = W[i];
    }
    if (tid < D) bl[tid] = b[tid];
    __syncthreads();

    int o = tid & 63;
    int row = blockIdx.x * 4 + (tid >> 6);
    if (row < N_NODES) {
        const float* hr = h + (long long)row * D;
        float acc = bl[o];
        #pragma unroll
        for (int d = 0; d < D; ++d) acc = fmaf(hr[d], Wl[o][d], acc);
        h[(long long)row * D + o] = fmaxf(acc, 0.0f);
    }
}

extern "C" void kernel_launch(void* const* d_in, const int* in_sizes, int n_in,
                              void* d_out, int out_size, void* d_ws, size_t ws_size,
                              hipStream_t stream) {
    const float* x   = (const float*)d_in[0];
    const int*   ei  = (const int*)d_in[1];   // int32 on device (harness narrows int64)
    const float* ea  = (const float*)d_in[2];
    const float* W   = (const float*)d_in[3];
    const float* b   = (const float*)d_in[4];
    const float* eps = (const float*)d_in[5];
    float* out = (float*)d_out;

    int n4 = (N_NODES * D) / 4;  // 1.6M float4s
    gine_init<<<(n4 + 255) / 256, 256, 0, stream>>>(x, eps, out, n4);

    int edges_per_block = 256 / 64;
    gine_edges<<<(N_EDGES + edges_per_block - 1) / edges_per_block, 256, 0, stream>>>(
        x, ei, ea, out);

    gine_linear<<<(N_NODES + 3) / 4, 256, 0, stream>>>(out, W, b);
}